// Round 1
// baseline (331.600 us; speedup 1.0000x reference)
//
#include <hip/hip_runtime.h>

// Single-head causal attention, fused per-batch kernel.
// B=2048, T=64, C=768, H=64. Inputs fp32: x, Wk, Wq, Wv ([in,out] layout).
// out[b,t,h] = softmax_causal(q k^T * 0.125) v,  q/k/v = x @ W.

#define BATCHES 2048
#define SEQ 64
#define CDIM 768
#define HDIM 64

typedef __bf16 bf16x8 __attribute__((ext_vector_type(8)));
typedef float f32x4v __attribute__((ext_vector_type(4)));
typedef unsigned short u16x8 __attribute__((ext_vector_type(8)));

__device__ __forceinline__ unsigned short f2bf(float f) {
  unsigned u = __builtin_bit_cast(unsigned, f);
  u += 0x7FFFu + ((u >> 16) & 1u);   // round-to-nearest-even
  return (unsigned short)(u >> 16);
}

// XOR swizzle in bf16 elements: byte ^= ((row&7)<<4)  <=>  elem col ^= ((row&7)<<3)
__device__ __forceinline__ int swz(int row, int col) {
  return row * 64 + (col ^ ((row & 7) << 3));
}

__device__ __forceinline__ f32x4v mfma16(bf16x8 a, bf16x8 b, f32x4v c) {
  return __builtin_amdgcn_mfma_f32_16x16x32_bf16(a, b, c, 0, 0, 0);
}

__device__ __forceinline__ bf16x8 lds_frag(const unsigned short* p, int row, int col) {
  return __builtin_bit_cast(bf16x8, *reinterpret_cast<const u16x8*>(p + swz(row, col)));
}

// Prep: Wt[p][h][c] = bf16(W_p[c][h]); p: 0=q, 1=k, 2=v. 3*64*768 elements.
__global__ __launch_bounds__(256) void prep_wt_kernel(
    const float* __restrict__ Wk, const float* __restrict__ Wq,
    const float* __restrict__ Wv, unsigned short* __restrict__ wt) {
  int i = blockIdx.x * 256 + threadIdx.x;
  if (i >= 3 * HDIM * CDIM) return;
  int p = i / (HDIM * CDIM);
  int rem = i - p * (HDIM * CDIM);
  int h = rem / CDIM;
  int c = rem - h * CDIM;
  const float* W = (p == 0) ? Wq : ((p == 1) ? Wk : Wv);
  wt[i] = f2bf(W[c * HDIM + h]);
}

__global__ __launch_bounds__(256) void head_fused_kernel(
    const float* __restrict__ x, const unsigned short* __restrict__ wt,
    float* __restrict__ out) {
  const int b = blockIdx.x;
  const int tid = threadIdx.x;
  const int w = tid >> 6;        // wave id 0..3, owns rows [16w, 16w+16)
  const int lane = tid & 63;
  const int lane15 = lane & 15;
  const int lhi = lane >> 4;

  __shared__ __align__(16) unsigned short k_lds[SEQ * HDIM];   // [s][h] swizzled
  __shared__ __align__(16) unsigned short vT_lds[HDIM * SEQ];  // [h][s] swizzled
  __shared__ __align__(16) unsigned short qp_lds[SEQ * HDIM];  // q then reused for P

  // ---------------- phase 1: q,k,v = x @ W (stream x from HBM, no LDS) --------
  // MFMA 16x16x32 A-frag: lane -> row = lane&15, k = (lane>>4)*8 + i
  const float* xl = x + (size_t)b * (SEQ * CDIM) + (16 * w + lane15) * CDIM + lhi * 8;
  const unsigned short* wtl = wt + lane15 * CDIM + lhi * 8;

  const f32x4v z4 = {0.f, 0.f, 0.f, 0.f};
  f32x4v accq[4], acck[4], accv[4];
  #pragma unroll
  for (int n = 0; n < 4; ++n) { accq[n] = z4; acck[n] = z4; accv[n] = z4; }

  for (int k0 = 0; k0 < CDIM; k0 += 32) {
    f32x4v xa = *reinterpret_cast<const f32x4v*>(xl + k0);
    f32x4v xb = *reinterpret_cast<const f32x4v*>(xl + k0 + 4);
    u16x8 ar;
    #pragma unroll
    for (int i = 0; i < 4; ++i) { ar[i] = f2bf(xa[i]); ar[4 + i] = f2bf(xb[i]); }
    bf16x8 a = __builtin_bit_cast(bf16x8, ar);
    #pragma unroll
    for (int n = 0; n < 4; ++n) {
      bf16x8 bq = __builtin_bit_cast(bf16x8,
          *reinterpret_cast<const u16x8*>(wtl + (0 * HDIM + 16 * n) * CDIM + k0));
      accq[n] = mfma16(a, bq, accq[n]);
      bf16x8 bk = __builtin_bit_cast(bf16x8,
          *reinterpret_cast<const u16x8*>(wtl + (1 * HDIM + 16 * n) * CDIM + k0));
      acck[n] = mfma16(a, bk, acck[n]);
      bf16x8 bv = __builtin_bit_cast(bf16x8,
          *reinterpret_cast<const u16x8*>(wtl + (2 * HDIM + 16 * n) * CDIM + k0));
      accv[n] = mfma16(a, bv, accv[n]);
    }
  }

  // epilogue: park k, vT, q as bf16 in swizzled LDS
  // C/D layout: col = lane&15, row = (lane>>4)*4 + j   [measured m89/m91]
  #pragma unroll
  for (int n = 0; n < 4; ++n) {
    int h = 16 * n + lane15;
    #pragma unroll
    for (int j = 0; j < 4; ++j) {
      int s = 16 * w + lhi * 4 + j;
      k_lds[swz(s, h)] = f2bf(acck[n][j]);
      vT_lds[swz(h, s)] = f2bf(accv[n][j]);
      qp_lds[swz(s, h)] = f2bf(accq[n][j]);
    }
  }
  __syncthreads();

  // ---------------- phase 2: S = q k^T (K over h) -----------------------------
  const int trow = 16 * w + lane15;
  bf16x8 aq0 = lds_frag(qp_lds, trow, lhi * 8);
  bf16x8 aq1 = lds_frag(qp_lds, trow, 32 + lhi * 8);
  f32x4v accS[4];
  #pragma unroll
  for (int n = 0; n < 4; ++n) accS[n] = z4;
  #pragma unroll
  for (int sB = 0; sB < 4; ++sB) {
    if (sB <= w) {  // causal: col blocks above the diagonal are all-masked
      bf16x8 bk0 = lds_frag(k_lds, 16 * sB + lane15, lhi * 8);
      bf16x8 bk1 = lds_frag(k_lds, 16 * sB + lane15, 32 + lhi * 8);
      accS[sB] = mfma16(aq0, bk0, accS[sB]);
      accS[sB] = mfma16(aq1, bk1, accS[sB]);
    }
  }

  // ---------------- phase 3: fp32 causal softmax, P -> bf16 LDS ---------------
  float rinv[4];
  #pragma unroll
  for (int j = 0; j < 4; ++j) {
    int t = 16 * w + lhi * 4 + j;
    float zv[4];
    float m = -3.0e38f;
    #pragma unroll
    for (int sB = 0; sB < 4; ++sB) {
      int s = 16 * sB + lane15;
      float zz = (sB <= w && s <= t) ? accS[sB][j] * 0.125f : -3.0e38f;
      zv[sB] = zz;
      m = fmaxf(m, zz);
    }
    #pragma unroll
    for (int off = 1; off < 16; off <<= 1) m = fmaxf(m, __shfl_xor(m, off));
    float sum = 0.f;
    float pv[4];
    #pragma unroll
    for (int sB = 0; sB < 4; ++sB) {
      float pe = __expf(zv[sB] - m);  // masked -> exp(-huge) = 0
      pv[sB] = pe;
      sum += pe;
    }
    #pragma unroll
    for (int off = 1; off < 16; off <<= 1) sum += __shfl_xor(sum, off);
    rinv[j] = 1.0f / sum;
    #pragma unroll
    for (int sB = 0; sB < 4; ++sB)
      qp_lds[swz(t, 16 * sB + lane15)] = f2bf(pv[sB]);
  }
  __syncthreads();  // safety: P visible before A-frag reads

  // ---------------- phase 4: O = P V (K over s) -------------------------------
  f32x4v accO[4];
  #pragma unroll
  for (int n = 0; n < 4; ++n) accO[n] = z4;
  #pragma unroll
  for (int s0 = 0; s0 < 64; s0 += 32) {
    if (s0 <= 16 * w + 15) {  // causal: later s-blocks are all zero for this wave
      bf16x8 ap = lds_frag(qp_lds, trow, s0 + lhi * 8);
      #pragma unroll
      for (int n = 0; n < 4; ++n) {
        bf16x8 bv = lds_frag(vT_lds, 16 * n + lane15, s0 + lhi * 8);
        accO[n] = mfma16(ap, bv, accO[n]);
      }
    }
  }

  // ---------------- phase 5: normalize + store fp32 ---------------------------
  float* op = out + (size_t)b * (SEQ * HDIM);
  #pragma unroll
  for (int n = 0; n < 4; ++n) {
    int h = 16 * n + lane15;
    #pragma unroll
    for (int j = 0; j < 4; ++j) {
      int t = 16 * w + lhi * 4 + j;
      op[t * HDIM + h] = accO[n][j] * rinv[j];
    }
  }
}

extern "C" void kernel_launch(void* const* d_in, const int* in_sizes, int n_in,
                              void* d_out, int out_size, void* d_ws, size_t ws_size,
                              hipStream_t stream) {
  const float* x  = (const float*)d_in[0];
  const float* Wk = (const float*)d_in[1];
  const float* Wq = (const float*)d_in[2];
  const float* Wv = (const float*)d_in[3];
  float* out = (float*)d_out;
  unsigned short* wt = (unsigned short*)d_ws;  // 3*64*768 bf16 = 288 KiB

  hipLaunchKernelGGL(prep_wt_kernel, dim3((3 * HDIM * CDIM + 255) / 256), dim3(256),
                     0, stream, Wk, Wq, Wv, wt);
  hipLaunchKernelGGL(head_fused_kernel, dim3(BATCHES), dim3(256), 0, stream,
                     x, wt, out);
}

// Round 3
// 119.703 us; speedup vs baseline: 2.7702x; 2.7702x over previous
//
#include <hip/hip_runtime.h>

// Single-head causal attention, fused per-batch kernel. Round 3:
// R2 (global_load_lds double-buffered staging) with the LDS-pointer-array
// compile failure fixed (byte-offset arithmetic instead of pointer arrays).
// B=2048, T=64, C=768, H=64. Inputs fp32: x, Wk, Wq, Wv ([in,out] layout).

#define BATCHES 2048
#define SEQ 64
#define CDIM 768
#define HDIM 64
#define NCHUNK 24  // 768 / 32

typedef __bf16 bf16x8 __attribute__((ext_vector_type(8)));
typedef float f32x4v __attribute__((ext_vector_type(4)));
typedef unsigned short u16x8 __attribute__((ext_vector_type(8)));

__device__ __forceinline__ unsigned short f2bf(float f) {
  return __builtin_bit_cast(unsigned short, (__bf16)f);
}

// XOR swizzle for 64-elem bf16 parking rows: elem col ^= ((row&7)<<3)
__device__ __forceinline__ int swz(int row, int col) {
  return row * 64 + (col ^ ((row & 7) << 3));
}

__device__ __forceinline__ f32x4v mfma16(bf16x8 a, bf16x8 b, f32x4v c) {
  return __builtin_amdgcn_mfma_f32_16x16x32_bf16(a, b, c, 0, 0, 0);
}

__device__ __forceinline__ bf16x8 lds_frag(const unsigned short* p, int row, int col) {
  return __builtin_bit_cast(bf16x8, *reinterpret_cast<const u16x8*>(p + swz(row, col)));
}

__device__ __forceinline__ void gl_lds16(const void* g, void* l) {
  __builtin_amdgcn_global_load_lds(
      (const __attribute__((address_space(1))) void*)g,
      (__attribute__((address_space(3))) void*)l, 16, 0, 0);
}

// Prep: write wt into chunk-slot order with granule swizzle pre-applied.
// ws element i: c = i/6144, slot = (i%6144)>>3, e = i&7;
// row = slot>>2 (0..191: mat*64+h), p = slot&3 (phys 16B granule);
// logical granule g = p ^ ((row>>1)&3); k = c*32 + g*8 + e.
__global__ __launch_bounds__(256) void prep_wt_kernel(
    const float* __restrict__ Wk, const float* __restrict__ Wq,
    const float* __restrict__ Wv, unsigned short* __restrict__ wt) {
  int i = blockIdx.x * 256 + threadIdx.x;
  if (i >= 3 * HDIM * CDIM) return;
  int c = i / 6144;
  int r2 = i - c * 6144;
  int slot = r2 >> 3;
  int e = r2 & 7;
  int row = slot >> 2;
  int p = slot & 3;
  int g = p ^ ((row >> 1) & 3);
  int k = c * 32 + g * 8 + e;
  int mat = row >> 6;
  int h = row & 63;
  const float* W = (mat == 0) ? Wq : ((mat == 1) ? Wk : Wv);
  wt[i] = f2bf(W[k * HDIM + h]);
}

__global__ __launch_bounds__(256) void head_fused_kernel(
    const float* __restrict__ x, const unsigned short* __restrict__ wt,
    float* __restrict__ out) {
  const int b = blockIdx.x;
  const int tid = threadIdx.x;
  const int w = tid >> 6;        // wave id 0..3, owns rows [16w, 16w+16)
  const int lane = tid & 63;
  const int lane15 = lane & 15;
  const int lhi = lane >> 4;

  // LDS: phase-1 staging [xb0 8K][xb1 8K][wb0 12K][wb1 12K] = 40 KB.
  // After phase 1 the first 24 KB are reused as parking: k | vT | q/P.
  __shared__ __align__(16) unsigned char smem[40960];
  unsigned short* k_lds  = (unsigned short*)smem;            // [s][h] swizzled
  unsigned short* vT_lds = (unsigned short*)(smem + 8192);   // [h][s] swizzled
  unsigned short* qp_lds = (unsigned short*)(smem + 16384);  // q then P

  // ---------------- phase-1 staging constants -------------------------------
  // x chunk image: [row 0..63][phys granule 0..7]x16B; phys p holds logical
  // granule p^(row&7). Source is per-lane pre-swizzled; LDS dest linear.
  const char* xsrc0;
  const char* xsrc1;
  int xdst0, xdst1;
  {
    int slot0 = (0 * 4 + w) * 64 + lane;
    int row0 = slot0 >> 3;
    int p0 = slot0 & 7;
    xsrc0 = (const char*)x + (size_t)b * (SEQ * CDIM * 4) + row0 * (CDIM * 4) +
            ((p0 ^ (row0 & 7)) * 16);
    xdst0 = (0 * 4 + w) * 1024;
    int slot1 = (1 * 4 + w) * 64 + lane;
    int row1 = slot1 >> 3;
    int p1 = slot1 & 7;
    xsrc1 = (const char*)x + (size_t)b * (SEQ * CDIM * 4) + row1 * (CDIM * 4) +
            ((p1 ^ (row1 & 7)) * 16);
    xdst1 = (1 * 4 + w) * 1024;
  }
  // wt chunk image is stored pre-swizzled in ws: staging is fully linear.
  const char* wsrc0 = (const char*)wt + ((0 * 4 + w) * 64 + lane) * 16;
  const char* wsrc1 = (const char*)wt + ((1 * 4 + w) * 64 + lane) * 16;
  const char* wsrc2 = (const char*)wt + ((2 * 4 + w) * 64 + lane) * 16;
  const int wdst0 = (0 * 4 + w) * 1024;
  const int wdst1 = (1 * 4 + w) * 1024;
  const int wdst2 = (2 * 4 + w) * 1024;

  const f32x4v z4 = {0.f, 0.f, 0.f, 0.f};
  f32x4v accq[4], acck[4], accv[4];
  #pragma unroll
  for (int n = 0; n < 4; ++n) { accq[n] = z4; acck[n] = z4; accv[n] = z4; }

  // prologue: stage chunk 0 into buffer 0
  {
    char* xb = (char*)smem;          // xbuf 0
    char* wb = (char*)smem + 16384;  // wbuf 0
    gl_lds16(xsrc0, xb + xdst0);
    gl_lds16(xsrc1, xb + xdst1);
    gl_lds16(wsrc0, wb + wdst0);
    gl_lds16(wsrc1, wb + wdst1);
    gl_lds16(wsrc2, wb + wdst2);
  }
  __syncthreads();

  const int arow = 16 * w + lane15;
  const int ag0 = (lhi * 2) ^ (arow & 7);
  const int ag1 = (lhi * 2 + 1) ^ (arow & 7);

  for (int c = 0; c < NCHUNK; ++c) {
    // stage chunk c+1 into the other buffer (fire-and-forget)
    if (c + 1 < NCHUNK) {
      int nb = (c + 1) & 1;
      char* xb = (char*)smem + nb * 8192;
      char* wb = (char*)smem + 16384 + nb * 12288;
      gl_lds16(xsrc0 + (c + 1) * 128, xb + xdst0);
      gl_lds16(xsrc1 + (c + 1) * 128, xb + xdst1);
      gl_lds16(wsrc0 + (c + 1) * 12288, wb + wdst0);
      gl_lds16(wsrc1 + (c + 1) * 12288, wb + wdst1);
      gl_lds16(wsrc2 + (c + 1) * 12288, wb + wdst2);
    }

    // compute chunk c from buffer c&1
    const float* xs = (const float*)((char*)smem + (c & 1) * 8192);
    const unsigned short* ws =
        (const unsigned short*)((char*)smem + 16384 + (c & 1) * 12288);

    f32x4v xa = *reinterpret_cast<const f32x4v*>(xs + arow * 32 + ag0 * 4);
    f32x4v xb4 = *reinterpret_cast<const f32x4v*>(xs + arow * 32 + ag1 * 4);
    u16x8 ar;
    #pragma unroll
    for (int i = 0; i < 4; ++i) { ar[i] = f2bf(xa[i]); ar[4 + i] = f2bf(xb4[i]); }
    bf16x8 a = __builtin_bit_cast(bf16x8, ar);

    #pragma unroll
    for (int n = 0; n < 4; ++n) {
      {  // mat 0 = q
        int brow = 0 * HDIM + 16 * n + lane15;
        int bp = lhi ^ ((brow >> 1) & 3);
        bf16x8 bq = __builtin_bit_cast(bf16x8,
            *reinterpret_cast<const u16x8*>(ws + brow * 32 + bp * 8));
        accq[n] = mfma16(a, bq, accq[n]);
      }
      {  // mat 1 = k
        int brow = 1 * HDIM + 16 * n + lane15;
        int bp = lhi ^ ((brow >> 1) & 3);
        bf16x8 bk = __builtin_bit_cast(bf16x8,
            *reinterpret_cast<const u16x8*>(ws + brow * 32 + bp * 8));
        acck[n] = mfma16(a, bk, acck[n]);
      }
      {  // mat 2 = v
        int brow = 2 * HDIM + 16 * n + lane15;
        int bp = lhi ^ ((brow >> 1) & 3);
        bf16x8 bv = __builtin_bit_cast(bf16x8,
            *reinterpret_cast<const u16x8*>(ws + brow * 32 + bp * 8));
        accv[n] = mfma16(a, bv, accv[n]);
      }
    }
    __syncthreads();  // drains staging (implicit vmcnt(0)) + buffer flip
  }

  // epilogue: park k, vT, q as bf16 in swizzled LDS (aliases staging buffers;
  // safe after the loop's final barrier).
  // C/D layout: col = lane&15, row = (lane>>4)*4 + j   [measured m89/m91]
  #pragma unroll
  for (int n = 0; n < 4; ++n) {
    int h = 16 * n + lane15;
    #pragma unroll
    for (int j = 0; j < 4; ++j) {
      int s = 16 * w + lhi * 4 + j;
      k_lds[swz(s, h)] = f2bf(acck[n][j]);
      vT_lds[swz(h, s)] = f2bf(accv[n][j]);
      qp_lds[swz(s, h)] = f2bf(accq[n][j]);
    }
  }
  __syncthreads();

  // ---------------- phase 2: S = q k^T (K over h) -----------------------------
  const int trow = 16 * w + lane15;
  bf16x8 aq0 = lds_frag(qp_lds, trow, lhi * 8);
  bf16x8 aq1 = lds_frag(qp_lds, trow, 32 + lhi * 8);
  f32x4v accS[4];
  #pragma unroll
  for (int n = 0; n < 4; ++n) accS[n] = z4;
  #pragma unroll
  for (int sB = 0; sB < 4; ++sB) {
    if (sB <= w) {  // causal: col blocks above the diagonal are all-masked
      bf16x8 bk0 = lds_frag(k_lds, 16 * sB + lane15, lhi * 8);
      bf16x8 bk1 = lds_frag(k_lds, 16 * sB + lane15, 32 + lhi * 8);
      accS[sB] = mfma16(aq0, bk0, accS[sB]);
      accS[sB] = mfma16(aq1, bk1, accS[sB]);
    }
  }

  // ---------------- phase 3: fp32 causal softmax, P -> bf16 LDS ---------------
  float rinv[4];
  #pragma unroll
  for (int j = 0; j < 4; ++j) {
    int t = 16 * w + lhi * 4 + j;
    float zv[4];
    float m = -3.0e38f;
    #pragma unroll
    for (int sB = 0; sB < 4; ++sB) {
      int s = 16 * sB + lane15;
      float zz = (sB <= w && s <= t) ? accS[sB][j] * 0.125f : -3.0e38f;
      zv[sB] = zz;
      m = fmaxf(m, zz);
    }
    #pragma unroll
    for (int off = 1; off < 16; off <<= 1) m = fmaxf(m, __shfl_xor(m, off));
    float sum = 0.f;
    float pv[4];
    #pragma unroll
    for (int sB = 0; sB < 4; ++sB) {
      float pe = __expf(zv[sB] - m);  // masked -> exp(-huge) = 0
      pv[sB] = pe;
      sum += pe;
    }
    #pragma unroll
    for (int off = 1; off < 16; off <<= 1) sum += __shfl_xor(sum, off);
    rinv[j] = 1.0f / sum;
    #pragma unroll
    for (int sB = 0; sB < 4; ++sB)
      qp_lds[swz(t, 16 * sB + lane15)] = f2bf(pv[sB]);
  }
  __syncthreads();  // P visible before A-frag reads

  // ---------------- phase 4: O = P V (K over s) -------------------------------
  f32x4v accO[4];
  #pragma unroll
  for (int n = 0; n < 4; ++n) accO[n] = z4;
  #pragma unroll
  for (int s0 = 0; s0 < 64; s0 += 32) {
    if (s0 <= 16 * w + 15) {  // causal: later s-blocks are all zero for this wave
      bf16x8 ap = lds_frag(qp_lds, trow, s0 + lhi * 8);
      #pragma unroll
      for (int n = 0; n < 4; ++n) {
        bf16x8 bv = lds_frag(vT_lds, 16 * n + lane15, s0 + lhi * 8);
        accO[n] = mfma16(ap, bv, accO[n]);
      }
    }
  }

  // ---------------- phase 5: normalize + store fp32 ---------------------------
  float* op = out + (size_t)b * (SEQ * HDIM);
  #pragma unroll
  for (int n = 0; n < 4; ++n) {
    int h = 16 * n + lane15;
    #pragma unroll
    for (int j = 0; j < 4; ++j) {
      int t = 16 * w + lhi * 4 + j;
      op[t * HDIM + h] = accO[n][j] * rinv[j];
    }
  }
}

extern "C" void kernel_launch(void* const* d_in, const int* in_sizes, int n_in,
                              void* d_out, int out_size, void* d_ws, size_t ws_size,
                              hipStream_t stream) {
  const float* x  = (const float*)d_in[0];
  const float* Wk = (const float*)d_in[1];
  const float* Wq = (const float*)d_in[2];
  const float* Wv = (const float*)d_in[3];
  float* out = (float*)d_out;
  unsigned short* wt = (unsigned short*)d_ws;  // 3*64*768 bf16 = 288 KiB

  hipLaunchKernelGGL(prep_wt_kernel, dim3((3 * HDIM * CDIM + 255) / 256), dim3(256),
                     0, stream, Wk, Wq, Wv, wt);
  hipLaunchKernelGGL(head_fused_kernel, dim3(BATCHES), dim3(256), 0, stream,
                     x, wt, out);
}

// Round 4
// 109.908 us; speedup vs baseline: 3.0171x; 1.0891x over previous
//
#include <hip/hip_runtime.h>

// Single-head causal attention, fused per-batch kernel. Round 4:
// counted-vmcnt software pipeline (two raw s_barriers per chunk, never
// draining the in-flight prefetch) replacing __syncthreads in the k-loop.
// B=2048, T=64, C=768, H=64. Inputs fp32: x, Wk, Wq, Wv ([in,out] layout).

#define BATCHES 2048
#define SEQ 64
#define CDIM 768
#define HDIM 64
#define NCHUNK 24  // 768 / 32

typedef __bf16 bf16x8 __attribute__((ext_vector_type(8)));
typedef float f32x4v __attribute__((ext_vector_type(4)));
typedef unsigned short u16x8 __attribute__((ext_vector_type(8)));

__device__ __forceinline__ unsigned short f2bf(float f) {
  return __builtin_bit_cast(unsigned short, (__bf16)f);
}

// XOR swizzle for 64-elem bf16 parking rows: elem col ^= ((row&7)<<3)
__device__ __forceinline__ int swz(int row, int col) {
  return row * 64 + (col ^ ((row & 7) << 3));
}

__device__ __forceinline__ f32x4v mfma16(bf16x8 a, bf16x8 b, f32x4v c) {
  return __builtin_amdgcn_mfma_f32_16x16x32_bf16(a, b, c, 0, 0, 0);
}

__device__ __forceinline__ bf16x8 lds_frag(const unsigned short* p, int row, int col) {
  return __builtin_bit_cast(bf16x8, *reinterpret_cast<const u16x8*>(p + swz(row, col)));
}

__device__ __forceinline__ void gl_lds16(const void* g, void* l) {
  __builtin_amdgcn_global_load_lds(
      (const __attribute__((address_space(1))) void*)g,
      (__attribute__((address_space(3))) void*)l, 16, 0, 0);
}

// Prep: write wt into chunk-slot order with granule swizzle pre-applied.
// ws element i: c = i/6144, slot = (i%6144)>>3, e = i&7;
// row = slot>>2 (0..191: mat*64+h), p = slot&3 (phys 16B granule);
// logical granule g = p ^ ((row>>1)&3); k = c*32 + g*8 + e.
__global__ __launch_bounds__(256) void prep_wt_kernel(
    const float* __restrict__ Wk, const float* __restrict__ Wq,
    const float* __restrict__ Wv, unsigned short* __restrict__ wt) {
  int i = blockIdx.x * 256 + threadIdx.x;
  if (i >= 3 * HDIM * CDIM) return;
  int c = i / 6144;
  int r2 = i - c * 6144;
  int slot = r2 >> 3;
  int e = r2 & 7;
  int row = slot >> 2;
  int p = slot & 3;
  int g = p ^ ((row >> 1) & 3);
  int k = c * 32 + g * 8 + e;
  int mat = row >> 6;
  int h = row & 63;
  const float* W = (mat == 0) ? Wq : ((mat == 1) ? Wk : Wv);
  wt[i] = f2bf(W[k * HDIM + h]);
}

__global__ __launch_bounds__(256) void head_fused_kernel(
    const float* __restrict__ x, const unsigned short* __restrict__ wt,
    float* __restrict__ out) {
  const int b = blockIdx.x;
  const int tid = threadIdx.x;
  const int w = tid >> 6;        // wave id 0..3, owns rows [16w, 16w+16)
  const int lane = tid & 63;
  const int lane15 = lane & 15;
  const int lhi = lane >> 4;

  // LDS: phase-1 staging [xb0 8K][xb1 8K][wb0 12K][wb1 12K] = 40 KB.
  // After phase 1 the first 24 KB are reused as parking: k | vT | q/P.
  __shared__ __align__(16) unsigned char smem[40960];
  unsigned short* k_lds  = (unsigned short*)smem;            // [s][h] swizzled
  unsigned short* vT_lds = (unsigned short*)(smem + 8192);   // [h][s] swizzled
  unsigned short* qp_lds = (unsigned short*)(smem + 16384);  // q then P

  // ---------------- phase-1 staging constants -------------------------------
  // x chunk image: [row 0..63][phys granule 0..7]x16B; phys p holds logical
  // granule p^(row&7). Source is per-lane pre-swizzled; LDS dest linear.
  const char* xsrc0;
  const char* xsrc1;
  int xdst0, xdst1;
  {
    int slot0 = (0 * 4 + w) * 64 + lane;
    int row0 = slot0 >> 3;
    int p0 = slot0 & 7;
    xsrc0 = (const char*)x + (size_t)b * (SEQ * CDIM * 4) + row0 * (CDIM * 4) +
            ((p0 ^ (row0 & 7)) * 16);
    xdst0 = (0 * 4 + w) * 1024;
    int slot1 = (1 * 4 + w) * 64 + lane;
    int row1 = slot1 >> 3;
    int p1 = slot1 & 7;
    xsrc1 = (const char*)x + (size_t)b * (SEQ * CDIM * 4) + row1 * (CDIM * 4) +
            ((p1 ^ (row1 & 7)) * 16);
    xdst1 = (1 * 4 + w) * 1024;
  }
  // wt chunk image is stored pre-swizzled in ws: staging is fully linear.
  const char* wsrc0 = (const char*)wt + ((0 * 4 + w) * 64 + lane) * 16;
  const char* wsrc1 = (const char*)wt + ((1 * 4 + w) * 64 + lane) * 16;
  const char* wsrc2 = (const char*)wt + ((2 * 4 + w) * 64 + lane) * 16;
  const int wdst0 = (0 * 4 + w) * 1024;
  const int wdst1 = (1 * 4 + w) * 1024;
  const int wdst2 = (2 * 4 + w) * 1024;

  const f32x4v z4 = {0.f, 0.f, 0.f, 0.f};
  f32x4v accq[4], acck[4], accv[4];
  #pragma unroll
  for (int n = 0; n < 4; ++n) { accq[n] = z4; acck[n] = z4; accv[n] = z4; }

  const int arow = 16 * w + lane15;
  const int ag0 = (lhi * 2) ^ (arow & 7);
  const int ag1 = (lhi * 2 + 1) ^ (arow & 7);

  // STAGE(cn, B): issue chunk cn's 5 fire-and-forget loads into buffer B.
  #define STAGE(cn, B)                                                         \
    do {                                                                       \
      char* xbp = (char*)smem + (B) * 8192;                                    \
      char* wbp = (char*)smem + 16384 + (B) * 12288;                           \
      gl_lds16(xsrc0 + (cn) * 128, xbp + xdst0);                               \
      gl_lds16(xsrc1 + (cn) * 128, xbp + xdst1);                               \
      gl_lds16(wsrc0 + (cn) * 12288, wbp + wdst0);                             \
      gl_lds16(wsrc1 + (cn) * 12288, wbp + wdst1);                             \
      gl_lds16(wsrc2 + (cn) * 12288, wbp + wdst2);                             \
    } while (0)

  // COMPUTE(B): consume buffer B (12 MFMAs).
  #define COMPUTE(B)                                                           \
    do {                                                                       \
      const float* xs = (const float*)((char*)smem + (B) * 8192);              \
      const unsigned short* ws =                                               \
          (const unsigned short*)((char*)smem + 16384 + (B) * 12288);          \
      f32x4v xa = *reinterpret_cast<const f32x4v*>(xs + arow * 32 + ag0 * 4);  \
      f32x4v xb4 = *reinterpret_cast<const f32x4v*>(xs + arow * 32 + ag1 * 4); \
      u16x8 ar;                                                                \
      _Pragma("unroll")                                                        \
      for (int i = 0; i < 4; ++i) { ar[i] = f2bf(xa[i]); ar[4 + i] = f2bf(xb4[i]); } \
      bf16x8 a = __builtin_bit_cast(bf16x8, ar);                               \
      _Pragma("unroll")                                                        \
      for (int n = 0; n < 4; ++n) {                                            \
        int brq = 0 * HDIM + 16 * n + lane15;                                  \
        int bpq = lhi ^ ((brq >> 1) & 3);                                      \
        bf16x8 bq = __builtin_bit_cast(bf16x8,                                 \
            *reinterpret_cast<const u16x8*>(ws + brq * 32 + bpq * 8));         \
        accq[n] = mfma16(a, bq, accq[n]);                                      \
        int brk = 1 * HDIM + 16 * n + lane15;                                  \
        int bpk = lhi ^ ((brk >> 1) & 3);                                      \
        bf16x8 bk = __builtin_bit_cast(bf16x8,                                 \
            *reinterpret_cast<const u16x8*>(ws + brk * 32 + bpk * 8));         \
        acck[n] = mfma16(a, bk, acck[n]);                                      \
        int brv = 2 * HDIM + 16 * n + lane15;                                  \
        int bpv = lhi ^ ((brv >> 1) & 3);                                      \
        bf16x8 bv = __builtin_bit_cast(bf16x8,                                 \
            *reinterpret_cast<const u16x8*>(ws + brv * 32 + bpv * 8));         \
        accv[n] = mfma16(a, bv, accv[n]);                                      \
      }                                                                        \
    } while (0)

  // MIDBAR: own chunk-c loads done (5 newer stay in flight), then sync.
  #define MIDBAR                                                   \
    do {                                                           \
      asm volatile("s_waitcnt vmcnt(5)" ::: "memory");             \
      __builtin_amdgcn_s_barrier();                                \
    } while (0)
  // ENDBAR: own LDS reads done, then sync (guards buffer reuse).
  #define ENDBAR                                                   \
    do {                                                           \
      asm volatile("s_waitcnt lgkmcnt(0)" ::: "memory");           \
      __builtin_amdgcn_s_barrier();                                \
    } while (0)

  // prologue: stage chunk 0 into buffer 0 (no wait yet)
  STAGE(0, 0);

  // steady state: chunks 0..21 in pairs (buffer parity compile-time)
  for (int c = 0; c < 22; c += 2) {
    STAGE(c + 1, 1);
    MIDBAR;
    COMPUTE(0);
    ENDBAR;
    STAGE(c + 2, 0);
    MIDBAR;
    COMPUTE(1);
    ENDBAR;
  }
  // c = 22: stage last chunk, compute 22
  STAGE(23, 1);
  MIDBAR;
  COMPUTE(0);
  ENDBAR;
  // c = 23: nothing left to stage
  asm volatile("s_waitcnt vmcnt(0)" ::: "memory");
  __builtin_amdgcn_s_barrier();
  COMPUTE(1);
  __syncthreads();  // all reads of xbuf1/wbuf1 done before parking overwrites

  #undef STAGE
  #undef COMPUTE
  #undef MIDBAR
  #undef ENDBAR

  // epilogue: park k, vT, q as bf16 in swizzled LDS (aliases staging buffers).
  // C/D layout: col = lane&15, row = (lane>>4)*4 + j   [measured m89/m91]
  #pragma unroll
  for (int n = 0; n < 4; ++n) {
    int h = 16 * n + lane15;
    #pragma unroll
    for (int j = 0; j < 4; ++j) {
      int s = 16 * w + lhi * 4 + j;
      k_lds[swz(s, h)] = f2bf(acck[n][j]);
      vT_lds[swz(h, s)] = f2bf(accv[n][j]);
      qp_lds[swz(s, h)] = f2bf(accq[n][j]);
    }
  }
  __syncthreads();

  // ---------------- phase 2: S = q k^T (K over h) -----------------------------
  const int trow = 16 * w + lane15;
  bf16x8 aq0 = lds_frag(qp_lds, trow, lhi * 8);
  bf16x8 aq1 = lds_frag(qp_lds, trow, 32 + lhi * 8);
  f32x4v accS[4];
  #pragma unroll
  for (int n = 0; n < 4; ++n) accS[n] = z4;
  #pragma unroll
  for (int sB = 0; sB < 4; ++sB) {
    if (sB <= w) {  // causal: col blocks above the diagonal are all-masked
      bf16x8 bk0 = lds_frag(k_lds, 16 * sB + lane15, lhi * 8);
      bf16x8 bk1 = lds_frag(k_lds, 16 * sB + lane15, 32 + lhi * 8);
      accS[sB] = mfma16(aq0, bk0, accS[sB]);
      accS[sB] = mfma16(aq1, bk1, accS[sB]);
    }
  }

  // ---------------- phase 3: fp32 causal softmax, P -> bf16 LDS ---------------
  float rinv[4];
  #pragma unroll
  for (int j = 0; j < 4; ++j) {
    int t = 16 * w + lhi * 4 + j;
    float zv[4];
    float m = -3.0e38f;
    #pragma unroll
    for (int sB = 0; sB < 4; ++sB) {
      int s = 16 * sB + lane15;
      float zz = (sB <= w && s <= t) ? accS[sB][j] * 0.125f : -3.0e38f;
      zv[sB] = zz;
      m = fmaxf(m, zz);
    }
    #pragma unroll
    for (int off = 1; off < 16; off <<= 1) m = fmaxf(m, __shfl_xor(m, off));
    float sum = 0.f;
    float pv[4];
    #pragma unroll
    for (int sB = 0; sB < 4; ++sB) {
      float pe = __expf(zv[sB] - m);  // masked -> exp(-huge) = 0
      pv[sB] = pe;
      sum += pe;
    }
    #pragma unroll
    for (int off = 1; off < 16; off <<= 1) sum += __shfl_xor(sum, off);
    rinv[j] = 1.0f / sum;
    #pragma unroll
    for (int sB = 0; sB < 4; ++sB)
      qp_lds[swz(t, 16 * sB + lane15)] = f2bf(pv[sB]);
  }
  __syncthreads();  // P visible before A-frag reads

  // ---------------- phase 4: O = P V (K over s) -------------------------------
  f32x4v accO[4];
  #pragma unroll
  for (int n = 0; n < 4; ++n) accO[n] = z4;
  #pragma unroll
  for (int s0 = 0; s0 < 64; s0 += 32) {
    if (s0 <= 16 * w + 15) {  // causal: later s-blocks are all zero for this wave
      bf16x8 ap = lds_frag(qp_lds, trow, s0 + lhi * 8);
      #pragma unroll
      for (int n = 0; n < 4; ++n) {
        bf16x8 bv = lds_frag(vT_lds, 16 * n + lane15, s0 + lhi * 8);
        accO[n] = mfma16(ap, bv, accO[n]);
      }
    }
  }

  // ---------------- phase 5: normalize + store fp32 ---------------------------
  float* op = out + (size_t)b * (SEQ * HDIM);
  #pragma unroll
  for (int n = 0; n < 4; ++n) {
    int h = 16 * n + lane15;
    #pragma unroll
    for (int j = 0; j < 4; ++j) {
      int t = 16 * w + lhi * 4 + j;
      op[t * HDIM + h] = accO[n][j] * rinv[j];
    }
  }
}

extern "C" void kernel_launch(void* const* d_in, const int* in_sizes, int n_in,
                              void* d_out, int out_size, void* d_ws, size_t ws_size,
                              hipStream_t stream) {
  const float* x  = (const float*)d_in[0];
  const float* Wk = (const float*)d_in[1];
  const float* Wq = (const float*)d_in[2];
  const float* Wv = (const float*)d_in[3];
  float* out = (float*)d_out;
  unsigned short* wt = (unsigned short*)d_ws;  // 3*64*768 bf16 = 288 KiB

  hipLaunchKernelGGL(prep_wt_kernel, dim3((3 * HDIM * CDIM + 255) / 256), dim3(256),
                     0, stream, Wk, Wq, Wv, wt);
  hipLaunchKernelGGL(head_fused_kernel, dim3(BATCHES), dim3(256), 0, stream,
                     x, wt, out);
}

// Round 5
// 106.534 us; speedup vs baseline: 3.1126x; 1.0317x over previous
//
#include <hip/hip_runtime.h>

// Single-head causal attention. Round 5: 2-batch 512-thread blocks,
// 3-deep x pipeline + 2-deep wt pipeline with derived counted vmcnt.
// B=2048, T=64, C=768, H=64. Inputs fp32: x, Wk, Wq, Wv ([in,out] layout).

#define BATCHES 2048
#define SEQ 64
#define CDIM 768
#define HDIM 64
#define NCHUNK 24  // 768 / 32

typedef __bf16 bf16x8 __attribute__((ext_vector_type(8)));
typedef float f32x4v __attribute__((ext_vector_type(4)));
typedef unsigned short u16x8 __attribute__((ext_vector_type(8)));

__device__ __forceinline__ unsigned short f2bf(float f) {
  return __builtin_bit_cast(unsigned short, (__bf16)f);
}

// XOR swizzle for 64-elem bf16 parking rows: elem col ^= ((row&7)<<3)
__device__ __forceinline__ int swz(int row, int col) {
  return row * 64 + (col ^ ((row & 7) << 3));
}

__device__ __forceinline__ f32x4v mfma16(bf16x8 a, bf16x8 b, f32x4v c) {
  return __builtin_amdgcn_mfma_f32_16x16x32_bf16(a, b, c, 0, 0, 0);
}

__device__ __forceinline__ bf16x8 lds_frag(const unsigned short* p, int row, int col) {
  return __builtin_bit_cast(bf16x8, *reinterpret_cast<const u16x8*>(p + swz(row, col)));
}

__device__ __forceinline__ void gl_lds16(const void* g, void* l) {
  __builtin_amdgcn_global_load_lds(
      (const __attribute__((address_space(1))) void*)g,
      (__attribute__((address_space(3))) void*)l, 16, 0, 0);
}

// Prep: ws chunk = 16 KB (8192 shorts): [slot 0..1023][e 0..7].
// slots 768..1023 are padding (never read from LDS). For slot<768:
// row = slot>>2 (mat*64+h), p = slot&3, g = p^((row>>1)&3), k = c*32+g*8+e.
__global__ __launch_bounds__(256) void prep_wt_kernel(
    const float* __restrict__ Wk, const float* __restrict__ Wq,
    const float* __restrict__ Wv, unsigned short* __restrict__ wt) {
  int i = blockIdx.x * 256 + threadIdx.x;
  if (i >= NCHUNK * 8192) return;
  int c = i >> 13;
  int r2 = i & 8191;
  int slot = r2 >> 3;
  if (slot >= 768) return;  // padding region: leave as-is (never consumed)
  int e = r2 & 7;
  int row = slot >> 2;
  int p = slot & 3;
  int g = p ^ ((row >> 1) & 3);
  int k = c * 32 + g * 8 + e;
  int mat = row >> 6;
  int h = row & 63;
  const float* W = (mat == 0) ? Wq : ((mat == 1) ? Wk : Wv);
  wt[i] = f2bf(W[k * HDIM + h]);
}

__global__ __launch_bounds__(512) void head_fused_kernel(
    const float* __restrict__ x, const unsigned short* __restrict__ wt,
    float* __restrict__ out) {
  const int bid = blockIdx.x;        // handles batches 2*bid, 2*bid+1
  const int tid = threadIdx.x;
  const int w = tid >> 6;            // wave 0..7
  const int ww = w & 3;              // wave-in-batch: rows [16ww, 16ww+16)
  const int bat = w >> 2;            // 0/1
  const int lane = tid & 63;
  const int lane15 = lane & 15;
  const int lhi = lane >> 4;

  // LDS 80 KB: [xb0 16K @0][xb1 @16K][xb2 @32K][wb0 @48K][wb1 @64K].
  // Parking (after streaming): batch r at r*24576: [k 8K][vT 8K][qp 8K].
  __shared__ __align__(16) unsigned char smem[81920];

  // ---- staging addresses ----------------------------------------------------
  // x chunk image per buffer: [batch r 8K][row 0..63][phys granule 0..7]x16B,
  // phys granule p holds logical granule p^(row&7); source pre-swizzled.
  const char* xsrc0;  // r = 0 -> batch 2*bid
  const char* xsrc1;  // r = 1 -> batch 2*bid+1
  {
    int s = w * 64 + lane;          // 0..511
    int row = s >> 3;
    int p = s & 7;
    size_t boff = row * (CDIM * 4) + ((p ^ (row & 7)) * 16);
    xsrc0 = (const char*)x + (size_t)(2 * bid + 0) * (SEQ * CDIM * 4) + boff;
    xsrc1 = (const char*)x + (size_t)(2 * bid + 1) * (SEQ * CDIM * 4) + boff;
  }
  const int xdst = (w * 64 + lane) * 16;  // within batch-r half: r*8192 + xdst

  // wt: fully linear (pre-swizzled in ws), chunk stride 16384 B.
  const char* wsrc0 = (const char*)wt + ((0 * 512 + w * 64 + lane) * 16);
  const char* wsrc1 = (const char*)wt + ((1 * 512 + w * 64 + lane) * 16);
  const int wdst0 = (0 * 512 + w * 64 + lane) * 16;
  const int wdst1 = (1 * 512 + w * 64 + lane) * 16;

  #define STAGE_X(cn, B)                                                    \
    do {                                                                    \
      char* xbp = (char*)smem + (B) * 16384;                                \
      gl_lds16(xsrc0 + (cn) * 128, xbp + 0 * 8192 + xdst);                  \
      gl_lds16(xsrc1 + (cn) * 128, xbp + 1 * 8192 + xdst);                  \
    } while (0)
  #define STAGE_W(cn, B)                                                    \
    do {                                                                    \
      char* wbp = (char*)smem + 49152 + (B) * 16384;                        \
      gl_lds16(wsrc0 + (cn) * 16384, wbp + wdst0);                          \
      gl_lds16(wsrc1 + (cn) * 16384, wbp + wdst1);                          \
    } while (0)

  const f32x4v z4 = {0.f, 0.f, 0.f, 0.f};
  f32x4v accq[4], acck[4], accv[4];
  #pragma unroll
  for (int n = 0; n < 4; ++n) { accq[n] = z4; acck[n] = z4; accv[n] = z4; }

  const int arow = 16 * ww + lane15;
  const int ag0 = (lhi * 2) ^ (arow & 7);
  const int ag1 = (lhi * 2 + 1) ^ (arow & 7);
  const int batoff = bat * 8192;

  // prologue (issue order defines the vm queue): W0,X0,W1,X1,X2
  STAGE_W(0, 0);
  STAGE_X(0, 0);
  STAGE_W(1, 1);
  STAGE_X(1, 1);
  STAGE_X(2, 2);

  #pragma unroll
  for (int c = 0; c < NCHUNK; ++c) {
    // derived waits: complete through {x(c), w(c)}; keep newer loads in flight
    if (c <= NCHUNK - 3)      asm volatile("s_waitcnt vmcnt(6)" ::: "memory");
    else if (c == NCHUNK - 2) asm volatile("s_waitcnt vmcnt(4)" ::: "memory");
    else                      asm volatile("s_waitcnt vmcnt(0)" ::: "memory");
    __builtin_amdgcn_s_barrier();

    {  // compute chunk c
      const float* xs = (const float*)((char*)smem + (c % 3) * 16384 + batoff);
      const unsigned short* ws =
          (const unsigned short*)((char*)smem + 49152 + (c & 1) * 16384);
      f32x4v xa = *reinterpret_cast<const f32x4v*>(xs + arow * 32 + ag0 * 4);
      f32x4v xb4 = *reinterpret_cast<const f32x4v*>(xs + arow * 32 + ag1 * 4);
      u16x8 ar;
      #pragma unroll
      for (int i = 0; i < 4; ++i) { ar[i] = f2bf(xa[i]); ar[4 + i] = f2bf(xb4[i]); }
      bf16x8 a = __builtin_bit_cast(bf16x8, ar);
      #pragma unroll
      for (int n = 0; n < 4; ++n) {
        int brq = 0 * HDIM + 16 * n + lane15;
        int bpq = lhi ^ ((brq >> 1) & 3);
        bf16x8 bq = __builtin_bit_cast(bf16x8,
            *reinterpret_cast<const u16x8*>(ws + brq * 32 + bpq * 8));
        accq[n] = mfma16(a, bq, accq[n]);
        int brk = 1 * HDIM + 16 * n + lane15;
        int bpk = lhi ^ ((brk >> 1) & 3);
        bf16x8 bk = __builtin_bit_cast(bf16x8,
            *reinterpret_cast<const u16x8*>(ws + brk * 32 + bpk * 8));
        acck[n] = mfma16(a, bk, acck[n]);
        int brv = 2 * HDIM + 16 * n + lane15;
        int bpv = lhi ^ ((brv >> 1) & 3);
        bf16x8 bv = __builtin_bit_cast(bf16x8,
            *reinterpret_cast<const u16x8*>(ws + brv * 32 + bpv * 8));
        accv[n] = mfma16(a, bv, accv[n]);
      }
    }

    asm volatile("s_waitcnt lgkmcnt(0)" ::: "memory");
    __builtin_amdgcn_s_barrier();

    // refill the buffers just freed (W before X: keeps queue order invariant)
    if (c + 2 < NCHUNK) STAGE_W(c + 2, c & 1);
    if (c + 3 < NCHUNK) STAGE_X(c + 3, c % 3);
  }

  #undef STAGE_X
  #undef STAGE_W

  // ---- parking: k, vT, q as bf16 in swizzled LDS (aliases x buffers) --------
  // C/D layout: col = lane&15, row = (lane>>4)*4 + j   [measured m89/m91]
  unsigned short* k_lds  = (unsigned short*)((char*)smem + bat * 24576);
  unsigned short* vT_lds = (unsigned short*)((char*)smem + bat * 24576 + 8192);
  unsigned short* qp_lds = (unsigned short*)((char*)smem + bat * 24576 + 16384);
  #pragma unroll
  for (int n = 0; n < 4; ++n) {
    int h = 16 * n + lane15;
    #pragma unroll
    for (int j = 0; j < 4; ++j) {
      int s = 16 * ww + lhi * 4 + j;
      k_lds[swz(s, h)] = f2bf(acck[n][j]);
      vT_lds[swz(h, s)] = f2bf(accv[n][j]);
      qp_lds[swz(s, h)] = f2bf(accq[n][j]);
    }
  }
  __syncthreads();

  // ---------------- phase 2: S = q k^T (K over h) -----------------------------
  const int trow = 16 * ww + lane15;
  bf16x8 aq0 = lds_frag(qp_lds, trow, lhi * 8);
  bf16x8 aq1 = lds_frag(qp_lds, trow, 32 + lhi * 8);
  f32x4v accS[4];
  #pragma unroll
  for (int n = 0; n < 4; ++n) accS[n] = z4;
  #pragma unroll
  for (int sB = 0; sB < 4; ++sB) {
    if (sB <= ww) {  // causal: col blocks above the diagonal are all-masked
      bf16x8 bk0 = lds_frag(k_lds, 16 * sB + lane15, lhi * 8);
      bf16x8 bk1 = lds_frag(k_lds, 16 * sB + lane15, 32 + lhi * 8);
      accS[sB] = mfma16(aq0, bk0, accS[sB]);
      accS[sB] = mfma16(aq1, bk1, accS[sB]);
    }
  }

  // ---------------- phase 3: fp32 causal softmax, P -> bf16 LDS ---------------
  float rinv[4];
  #pragma unroll
  for (int j = 0; j < 4; ++j) {
    int t = 16 * ww + lhi * 4 + j;
    float zv[4];
    float m = -3.0e38f;
    #pragma unroll
    for (int sB = 0; sB < 4; ++sB) {
      int s = 16 * sB + lane15;
      float zz = (sB <= ww && s <= t) ? accS[sB][j] * 0.125f : -3.0e38f;
      zv[sB] = zz;
      m = fmaxf(m, zz);
    }
    #pragma unroll
    for (int off = 1; off < 16; off <<= 1) m = fmaxf(m, __shfl_xor(m, off));
    float sum = 0.f;
    float pv[4];
    #pragma unroll
    for (int sB = 0; sB < 4; ++sB) {
      float pe = __expf(zv[sB] - m);  // masked -> exp(-huge) = 0
      pv[sB] = pe;
      sum += pe;
    }
    #pragma unroll
    for (int off = 1; off < 16; off <<= 1) sum += __shfl_xor(sum, off);
    rinv[j] = 1.0f / sum;
    #pragma unroll
    for (int sB = 0; sB < 4; ++sB)
      qp_lds[swz(t, 16 * sB + lane15)] = f2bf(pv[sB]);
  }
  __syncthreads();  // P visible before A-frag reads

  // ---------------- phase 4: O = P V (K over s) -------------------------------
  f32x4v accO[4];
  #pragma unroll
  for (int n = 0; n < 4; ++n) accO[n] = z4;
  #pragma unroll
  for (int s0 = 0; s0 < 64; s0 += 32) {
    if (s0 <= 16 * ww + 15) {  // causal: later s-blocks all zero for this wave
      bf16x8 ap = lds_frag(qp_lds, trow, s0 + lhi * 8);
      #pragma unroll
      for (int n = 0; n < 4; ++n) {
        bf16x8 bv = lds_frag(vT_lds, 16 * n + lane15, s0 + lhi * 8);
        accO[n] = mfma16(ap, bv, accO[n]);
      }
    }
  }

  // ---------------- phase 5: normalize + store fp32 ---------------------------
  float* op = out + (size_t)(2 * bid + bat) * (SEQ * HDIM);
  #pragma unroll
  for (int n = 0; n < 4; ++n) {
    int h = 16 * n + lane15;
    #pragma unroll
    for (int j = 0; j < 4; ++j) {
      int t = 16 * ww + lhi * 4 + j;
      op[t * HDIM + h] = accO[n][j] * rinv[j];
    }
  }
}

extern "C" void kernel_launch(void* const* d_in, const int* in_sizes, int n_in,
                              void* d_out, int out_size, void* d_ws, size_t ws_size,
                              hipStream_t stream) {
  const float* x  = (const float*)d_in[0];
  const float* Wk = (const float*)d_in[1];
  const float* Wq = (const float*)d_in[2];
  const float* Wv = (const float*)d_in[3];
  float* out = (float*)d_out;
  unsigned short* wt = (unsigned short*)d_ws;  // 24 chunks x 16 KB = 384 KiB

  hipLaunchKernelGGL(prep_wt_kernel, dim3((NCHUNK * 8192 + 255) / 256), dim3(256),
                     0, stream, Wk, Wq, Wv, wt);
  hipLaunchKernelGGL(head_fused_kernel, dim3(BATCHES / 2), dim3(512), 0, stream,
                     x, wt, out);
}